// Round 10
// baseline (166.851 us; speedup 1.0000x reference)
//
#include <hip/hip_runtime.h>
#include <hip/hip_bf16.h>

#define N_NODES 100000
#define DEG 16
#define C 128            // C_IN == C_OUT == 128
#define NTILES 6250      // 100000 / 16
#define FBLOCKS 782      // 782*4 waves * 2 tiles = 6256 >= NTILES

typedef __attribute__((ext_vector_type(8))) short short8;
typedef __attribute__((ext_vector_type(4))) float f32x4;

// fp32 -> bf16 bits, round-to-nearest-even (matches numpy)
__device__ inline unsigned short f2bf(float f) {
    unsigned int u = __builtin_bit_cast(unsigned int, f);
    u += 0x7fffu + ((u >> 16) & 1u);
    return (unsigned short)(u >> 16);
}

// ---------------------------------------------------------------------------
// Kernel 0 (prep): x8[i][k] = rint(x[i][k] * 127/rowmax_i) + 128  (BIASED u8)
//                  scale[i] = rowmax_i/127 * out_norm_i           (norm folded)
// One 16-lane group per row. x8/scale live in d_ws.
// ---------------------------------------------------------------------------
__global__ __launch_bounds__(256, 8)
void gcn_prep_kernel(const float* __restrict__ x, const int* __restrict__ colptr,
                     unsigned char* __restrict__ x8, float* __restrict__ scale)
{
    int tid = threadIdx.x;
    int wave = tid >> 6;
    int lane = tid & 63;
    int row = (blockIdx.x * 4 + wave) * 4 + (lane >> 4);   // 16 rows/block
    int cg = lane & 15;                                    // 8-col chunk

    const float* xr = x + (long)row * C + cg * 8;
    f32x4 a = *reinterpret_cast<const f32x4*>(xr);
    f32x4 b = *reinterpret_cast<const f32x4*>(xr + 4);

    float m = fmaxf(fmaxf(fmaxf(fabsf(a[0]), fabsf(a[1])), fmaxf(fabsf(a[2]), fabsf(a[3]))),
                    fmaxf(fmaxf(fabsf(b[0]), fabsf(b[1])), fmaxf(fabsf(b[2]), fabsf(b[3]))));
    m = fmaxf(m, __shfl_xor(m, 1));
    m = fmaxf(m, __shfl_xor(m, 2));
    m = fmaxf(m, __shfl_xor(m, 4));
    m = fmaxf(m, __shfl_xor(m, 8));
    m = fmaxf(m, 1e-30f);

    float inv = 127.0f / m;
    unsigned int lo = 0, hi = 0;
    lo |= ((unsigned int)((int)rintf(a[0] * inv) + 128));
    lo |= ((unsigned int)((int)rintf(a[1] * inv) + 128)) << 8;
    lo |= ((unsigned int)((int)rintf(a[2] * inv) + 128)) << 16;
    lo |= ((unsigned int)((int)rintf(a[3] * inv) + 128)) << 24;
    hi |= ((unsigned int)((int)rintf(b[0] * inv) + 128));
    hi |= ((unsigned int)((int)rintf(b[1] * inv) + 128)) << 8;
    hi |= ((unsigned int)((int)rintf(b[2] * inv) + 128)) << 16;
    hi |= ((unsigned int)((int)rintf(b[3] * inv) + 128)) << 24;

    uint2 pk; pk.x = lo; pk.y = hi;
    *reinterpret_cast<uint2*>(x8 + (long)row * C + cg * 8) = pk;

    if (cg == 0) {
        int od = colptr[row + 1] - colptr[row];
        scale[row] = m * (1.0f / 127.0f) * rsqrtf((float)od);
    }
}

// dequant 16 gathered rows -> packed bf16x8 (16 B) for one (node,8-col) slot
__device__ __forceinline__ uint4 dq_pack(const uint2* v, float mysc, int gb, float innorm)
{
    float acc[8] = {0.f, 0.f, 0.f, 0.f, 0.f, 0.f, 0.f, 0.f};
    float ssum = 0.f;
#pragma unroll
    for (int e = 0; e < 16; ++e) {
        float s = __shfl(mysc, gb + e);
        ssum += s;
        unsigned int a = v[e].x, b = v[e].y;
        acc[0] += s * (float)(a & 0xff);
        acc[1] += s * (float)((a >> 8) & 0xff);
        acc[2] += s * (float)((a >> 16) & 0xff);
        acc[3] += s * (float)(a >> 24);
        acc[4] += s * (float)(b & 0xff);
        acc[5] += s * (float)((b >> 8) & 0xff);
        acc[6] += s * (float)((b >> 16) & 0xff);
        acc[7] += s * (float)(b >> 24);
    }
    float fix = 128.0f * ssum;
    uint4 o;
    o.x = (unsigned int)f2bf((acc[0] - fix) * innorm) |
          ((unsigned int)f2bf((acc[1] - fix) * innorm) << 16);
    o.y = (unsigned int)f2bf((acc[2] - fix) * innorm) |
          ((unsigned int)f2bf((acc[3] - fix) * innorm) << 16);
    o.z = (unsigned int)f2bf((acc[4] - fix) * innorm) |
          ((unsigned int)f2bf((acc[5] - fix) * innorm) << 16);
    o.w = (unsigned int)f2bf((acc[6] - fix) * innorm) |
          ((unsigned int)f2bf((acc[7] - fix) * innorm) << 16);
    return o;
}

// ---------------------------------------------------------------------------
// Fused aggr+GEMM, WAVE-DECOUPLED: each wave owns whole 16-node tiles.
// Per tile: gather 16 nodes (4/subgroup, processed in PAIRS -> 32-deep uint2
// MLP), dequant into the wave's PRIVATE LDS A-quadrant (no barrier; lgkmcnt
// fence), then 8 col-tiles of MFMA with B-frags ds_read_b128 from the
// frag-linear W in LDS (staged once per block = the only __syncthreads).
// ---------------------------------------------------------------------------
__global__ __launch_bounds__(256, 3)
void gcn_fused_kernel(const unsigned char* __restrict__ x8,
                      const float* __restrict__ scale,
                      const int* __restrict__ rowptr,
                      const int* __restrict__ colind,
                      const float* __restrict__ wmat,
                      const float* __restrict__ bias,
                      float* __restrict__ out)
{
    __shared__ unsigned short wfrag[32 * 64 * 8];   // 32 KB, frag-linear (R2)
    __shared__ uint4 atile[4][16 * 16];             // 4 KB per wave, private

    int tid  = threadIdx.x;
    int wv   = tid >> 6;
    int lane = tid & 63;
    int g    = lane >> 4;      // subgroup 0..3 (4 nodes each; also MFMA quad)
    int cl   = lane & 15;      // col chunk (producer) / m-row (consumer)
    int gb   = lane & 48;

    // stage W into frag-linear LDS (once per block)
    for (int i0 = tid * 4; i0 < C * C; i0 += 1024) {
        f32x4 ww = *reinterpret_cast<const f32x4*>(wmat + i0);
#pragma unroll
        for (int d = 0; d < 4; ++d) {
            int i = i0 + d;
            int k = i >> 7, n = i & 127;
            int nt = n >> 4, lr = n & 15;
            int kc = k >> 5, quad = (k >> 3) & 3, j = k & 7;
            wfrag[((((nt << 2) + kc) << 6) + (quad << 4) + lr) * 8 + j] = f2bf(ww[d]);
        }
    }
    __syncthreads();           // the only block-wide barrier

    float bv[8];
#pragma unroll
    for (int nt = 0; nt < 8; ++nt) bv[nt] = bias[nt * 16 + cl];

    uint4* myat = atile[wv];

    for (int t = blockIdx.x * 4 + wv; t < NTILES; t += FBLOCKS * 4) {
        // ---- gather + dequant 16 nodes, two at a time (32-deep MLP) ----
#pragma unroll
        for (int pr = 0; pr < 2; ++pr) {
            int r0 = pr * 2, r1 = pr * 2 + 1;
            int node0 = t * 16 + g * 4 + r0;
            int node1 = t * 16 + g * 4 + r1;
            int b0 = rowptr[node0];
            int b1 = rowptr[node1];
            float in0 = rsqrtf((float)(rowptr[node0 + 1] - b0));
            float in1 = rsqrtf((float)(rowptr[node1 + 1] - b1));
            int i0 = colind[b0 + cl];
            int i1 = colind[b1 + cl];
            float s0 = scale[i0];
            float s1 = scale[i1];

            uint2 v0[16], v1[16];
#pragma unroll
            for (int e = 0; e < 16; ++e) {
                int j = __shfl(i0, gb + e);
                v0[e] = *reinterpret_cast<const uint2*>(x8 + (j << 7) + (cl << 3));
            }
#pragma unroll
            for (int e = 0; e < 16; ++e) {
                int j = __shfl(i1, gb + e);
                v1[e] = *reinterpret_cast<const uint2*>(x8 + (j << 7) + (cl << 3));
            }
            int rr0 = g * 4 + r0, rr1 = g * 4 + r1;
            myat[rr0 * 16 + (cl ^ (rr0 & 7))] = dq_pack(v0, s0, gb, in0);
            myat[rr1 * 16 + (cl ^ (rr1 & 7))] = dq_pack(v1, s1, gb, in1);
        }

        // same-wave LDS write->read ordering
        asm volatile("s_waitcnt lgkmcnt(0)" ::: "memory");

        // ---- A-frags from the wave's private quadrant ----
        short8 af[4];
#pragma unroll
        for (int kc = 0; kc < 4; ++kc)
            af[kc] = __builtin_bit_cast(short8,
                myat[cl * 16 + ((kc * 4 + g) ^ (cl & 7))]);

        // ---- 8 col-tiles of MFMA, B from wfrag ----
#pragma unroll
        for (int nt = 0; nt < 8; ++nt) {
            f32x4 acc = {0.f, 0.f, 0.f, 0.f};
#pragma unroll
            for (int kc = 0; kc < 4; ++kc) {
                short8 b = *reinterpret_cast<const short8*>(
                    &wfrag[((((nt << 2) + kc) << 6) + lane) * 8]);
                acc = __builtin_amdgcn_mfma_f32_16x16x32_bf16(af[kc], b, acc, 0, 0, 0);
            }
            // D layout: col = lane&15 (=cl), row = g*4 + reg (m89-verified)
            float* op = out + (long)(t * 16 + g * 4) * C + nt * 16 + cl;
#pragma unroll
            for (int r = 0; r < 4; ++r)
                op[r * C] = acc[r] + bv[nt];
        }
    }
}

extern "C" void kernel_launch(void* const* d_in, const int* in_sizes, int n_in,
                              void* d_out, int out_size, void* d_ws, size_t ws_size,
                              hipStream_t stream) {
    const float* x      = (const float*)d_in[0];
    const float* w      = (const float*)d_in[1];
    const float* bias   = (const float*)d_in[2];
    const int*   rowptr = (const int*)d_in[3];
    const int*   colind = (const int*)d_in[4];
    const int*   colptr = (const int*)d_in[5];
    // d_in[6] = rowind (unused by the reference math)
    float* out = (float*)d_out;

    // scratch in d_ws: biased-u8 x (12.8 MB) + scale (0.4 MB)
    unsigned char* x8    = (unsigned char*)d_ws;
    float*         scale = (float*)((char*)d_ws + (size_t)N_NODES * C);

    gcn_prep_kernel<<<6250, 256, 0, stream>>>(x, colptr, x8, scale);
    gcn_fused_kernel<<<FBLOCKS, 256, 0, stream>>>(x8, scale, rowptr, colind,
                                                  w, bias, out);
}